// Round 8
// baseline (251.055 us; speedup 1.0000x reference)
//
#include <hip/hip_runtime.h>

typedef unsigned short UST;
typedef __attribute__((ext_vector_type(8))) short bf16x8;
typedef __attribute__((ext_vector_type(8))) unsigned short us8;
typedef __attribute__((ext_vector_type(4))) float f32x4;

__device__ __forceinline__ UST f2bf(float f) {
  union { float f; unsigned int u; } x; x.f = f;
  unsigned int r = x.u + 0x7fffu + ((x.u >> 16) & 1u);
  return (UST)(r >> 16);
}
__device__ __forceinline__ float bf2f(UST h) {
  union { unsigned int u; float f; } x; x.u = ((unsigned int)h) << 16;
  return x.f;
}

__device__ __forceinline__ void sync_lds() {
  asm volatile("s_waitcnt lgkmcnt(0)\n\ts_barrier" ::: "memory");
}
__device__ __forceinline__ void barrier_nowait() {
  asm volatile("s_barrier" ::: "memory");
}

typedef const __attribute__((address_space(1))) void g_void;
typedef __attribute__((address_space(3))) void lds_void;
__device__ __forceinline__ void gload16(const UST* g, UST* l) {
  __builtin_amdgcn_global_load_lds((g_void*)g, (lds_void*)l, 16, 0, 0);
}

// ---- prep: GroupNorm (single pass) + weight conversion ---------------------
__global__ __launch_bounds__(256) void prep(
    const float* __restrict__ inp, const float* __restrict__ gamma,
    const float* __restrict__ beta, UST* __restrict__ Xnt,
    const float4* __restrict__ wq, const float4* __restrict__ wk,
    const float4* __restrict__ wv, const float4* __restrict__ wo,
    ushort4* __restrict__ oqkv, ushort4* __restrict__ owo,
    const float4* __restrict__ bq4, const float4* __restrict__ bk4,
    const float4* __restrict__ bv4, float4* __restrict__ bqkv4) {
  const int tid = threadIdx.x;
  if (blockIdx.x >= 512) {
    const int wb = blockIdx.x - 512;
    int i = wb * 256 + tid;
    float4 v;
    v = wq[i]; oqkv[i]          = make_ushort4(f2bf(v.x), f2bf(v.y), f2bf(v.z), f2bf(v.w));
    v = wk[i]; oqkv[i + 65536]  = make_ushort4(f2bf(v.x), f2bf(v.y), f2bf(v.z), f2bf(v.w));
    v = wv[i]; oqkv[i + 131072] = make_ushort4(f2bf(v.x), f2bf(v.y), f2bf(v.z), f2bf(v.w));
    v = wo[i]; owo[i]           = make_ushort4(f2bf(v.x), f2bf(v.y), f2bf(v.z), f2bf(v.w));
    if (wb < 2) {
      int t = wb * 256 + tid;
      if (t < 384) bqkv4[t] = (t < 128) ? bq4[t] : (t < 256 ? bk4[t - 128] : bv4[t - 256]);
    }
    return;
  }
  const int g = blockIdx.x & 31, b = blockIdx.x >> 5;
  const float4* p4 = (const float4*)(inp + ((size_t)b * 32 + g) * 16384);
  float x[16][4];
  float s = 0.f, ss = 0.f;
#pragma unroll
  for (int i = 0; i < 16; i++) {
    float4 t = p4[tid + i * 256];
    x[i][0] = t.x; x[i][1] = t.y; x[i][2] = t.z; x[i][3] = t.w;
    s += t.x + t.y + t.z + t.w;
    ss += t.x * t.x + t.y * t.y + t.z * t.z + t.w * t.w;
  }
  for (int o = 32; o >= 1; o >>= 1) { s += __shfl_xor(s, o); ss += __shfl_xor(ss, o); }
  __shared__ float red[8];
  __shared__ float mu_s, rstd_s;
  const int w = tid >> 6;
  if ((tid & 63) == 0) { red[w * 2] = s; red[w * 2 + 1] = ss; }
  __syncthreads();
  if (tid == 0) {
    float S1 = red[0] + red[2] + red[4] + red[6];
    float S2 = red[1] + red[3] + red[5] + red[7];
    float mu = S1 * (1.f / 16384.f);
    float var = S2 * (1.f / 16384.f) - mu * mu;
    mu_s = mu; rstd_s = rsqrtf(var + 1e-6f);
  }
  __syncthreads();
  const float mu = mu_s, rstd = rstd_s;
#pragma unroll
  for (int o2 = 0; o2 < 2; o2++) {
    const int ccg = g * 2 + o2;
    float sc[8], sh[8];
#pragma unroll
    for (int j = 0; j < 8; j++) {
      int ch = ccg * 8 + j;
      sc[j] = gamma[ch] * rstd;
      sh[j] = beta[ch] - mu * sc[j];
    }
#pragma unroll
    for (int m = 0; m < 4; m++) {
      us8 v;
#pragma unroll
      for (int j = 0; j < 8; j++) v[j] = f2bf(x[o2 * 8 + j][m] * sc[j] + sh[j]);
      *(us8*)(Xnt + (size_t)b * 524288 + (size_t)ccg * 8192 + (size_t)(4 * tid + m) * 8) = v;
    }
  }
}

// ---- attn: fused P=exp(QK^T*scale) softmax + At=(P V^T)/l ------------------
// One block per (batch b, 64 n-rows). 512 thr = 8 waves, barrier-free loops.
// Stage 1 (S^T trick): wave w owns m-rows [w*128, w*128+128) in 2 mg-halves:
//   s[im][jn] = mfma(K-frag, Q-frag) -> D rows = m, cols = n. Lane holds
//   4 CONSECUTIVE m per (im,jn) -> vectorized ushort4 P-writes to LDS.
//   K/Q frags loaded DIRECT from global (QKt row n: Q cols 0..511, K 512..1023).
//   P LDS layout: row n (0..63) x 128 chunks of 8 bf16; chunk stored at slot
//   chunk ^ ((n&7)<<2) -> stage-2 ds_read_b128 conflict-floor.
//   l: in-register bf16-rounded sums, quad-shfl reduce, cross-wave via lbuf.
// Stage 2: o[i][jc] = mfma(P-frag(LDS), V-frag(global, (c,m) layout ->
//   contiguous 16B/lane)). V double-buffered in regs (static names).
// Epilogue: o * (1/l[row]) -> LDS transpose (pitch 520) -> us8 store At[n][c].
//   (r7 BUG FIXED: store loop was it<4 / q>>5 / q&31 -> only c 0..255 written,
//    c 256..511 kept stale Xnt data (At aliases Xnt) -> absmax 4.0. Now it<8,
//    row = q>>6, cc = q&63: full 64x512 coverage.)
// XCD pinning: lin%8 selects batch pair -> L2 reuse of K/V per XCD.
__global__ __launch_bounds__(512, 2) void attn(
    const UST* __restrict__ QKt, const UST* __restrict__ V,
    UST* __restrict__ At, float scale) {
  __shared__ __align__(16) UST Ps[65536];   // 128 KB: P, then reused as obuf
  __shared__ float lbuf[512];
  __shared__ __align__(16) float linv[64];

  const int tid = threadIdx.x;
  const int lin = blockIdx.x;                 // 256 blocks
  const int b  = (lin & 7) * 2 + (lin >> 7);  // XCD k -> batches {2k, 2k+1}
  const int n0 = ((lin >> 3) & 15) * 64;

  const UST* qk = QKt + (size_t)b * 1048576;
  const UST* vb = V   + (size_t)b * 524288;
  UST* ob       = At  + (size_t)b * 524288 + (size_t)n0 * 512;

  const int w = tid >> 6, lane = tid & 63;
  const int quad = lane >> 4, l16 = lane & 15;
  const int xr = (l16 & 7) << 2;  // P chunk-slot XOR (bits [4:2])

  // ---------------- stage 1: P = exp(S * scale) ----------------
  int qoff[4];
#pragma unroll
  for (int jn = 0; jn < 4; jn++)
    qoff[jn] = (n0 + jn * 16 + l16) * 1024 + quad * 8;

  float lp[4] = {0.f, 0.f, 0.f, 0.f};

#define LDS1(KF, QF, KS)                                          \
  _Pragma("unroll") for (int t = 0; t < 4; t++) {                 \
    KF[t] = *(const bf16x8*)(qk + koff[t] + (KS) * 32);           \
    QF[t] = *(const bf16x8*)(qk + qoff[t] + (KS) * 32);           \
  }
#define MM1(KF, QF)                                               \
  __builtin_amdgcn_s_setprio(1);                                  \
  _Pragma("unroll") for (int im = 0; im < 4; im++)                \
    _Pragma("unroll") for (int jn = 0; jn < 4; jn++)              \
      s[im][jn] = __builtin_amdgcn_mfma_f32_16x16x32_bf16(        \
          KF[im], QF[jn], s[im][jn], 0, 0, 0);                    \
  __builtin_amdgcn_s_setprio(0);

#pragma unroll
  for (int mg = 0; mg < 2; ++mg) {
    int koff[4];
#pragma unroll
    for (int im = 0; im < 4; im++)
      koff[im] = (w * 128 + mg * 64 + im * 16 + l16) * 1024 + 512 + quad * 8;

    f32x4 s[4][4];
#pragma unroll
    for (int i = 0; i < 4; i++)
#pragma unroll
      for (int j = 0; j < 4; j++) s[i][j] = f32x4{0.f, 0.f, 0.f, 0.f};

    bf16x8 kA[4], qA[4], kB[4], qB[4];
    LDS1(kA, qA, 0)
#pragma unroll
    for (int ks2 = 0; ks2 < 8; ks2++) {
      LDS1(kB, qB, 2 * ks2 + 1)
      MM1(kA, qA)
      if (ks2 < 7) { LDS1(kA, qA, 2 * ks2 + 2) }
      MM1(kB, qB)
    }

    // P write (ushort4: 4 consecutive m per lane) + l partials (bf16-rounded)
#pragma unroll
    for (int im = 0; im < 4; im++) {
      const int chunk = w * 16 + mg * 8 + im * 2 + (quad >> 1);
#pragma unroll
      for (int jn = 0; jn < 4; jn++) {
        ushort4 pv;
        float e0 = __expf(s[im][jn][0] * scale);
        float e1 = __expf(s[im][jn][1] * scale);
        float e2 = __expf(s[im][jn][2] * scale);
        float e3 = __expf(s[im][jn][3] * scale);
        pv.x = f2bf(e0); pv.y = f2bf(e1); pv.z = f2bf(e2); pv.w = f2bf(e3);
        lp[jn] += bf2f(pv.x) + bf2f(pv.y) + bf2f(pv.z) + bf2f(pv.w);
        const int nl = jn * 16 + l16;
        *(ushort4*)&Ps[nl * 1024 + (chunk ^ xr) * 8 + (quad & 1) * 4] = pv;
      }
    }
  }
#undef LDS1
#undef MM1

  // cross-quad reduce (quad is an m-component) then cross-wave via lbuf
#pragma unroll
  for (int jn = 0; jn < 4; jn++) {
    lp[jn] += __shfl_xor(lp[jn], 16);
    lp[jn] += __shfl_xor(lp[jn], 32);
  }
  if (quad == 0) {
#pragma unroll
    for (int jn = 0; jn < 4; jn++) lbuf[w * 64 + jn * 16 + l16] = lp[jn];
  }
  sync_lds();
  if (tid < 64) {
    float sa = 0.f;
#pragma unroll
    for (int ww = 0; ww < 8; ww++) sa += lbuf[ww * 64 + tid];
    linv[tid] = 1.0f / sa;
  }
  sync_lds();

  // ---------------- stage 2: o = P * V^T ----------------
  f32x4 o[4][4];
#pragma unroll
  for (int i = 0; i < 4; i++)
#pragma unroll
    for (int j = 0; j < 4; j++) o[i][j] = f32x4{0.f, 0.f, 0.f, 0.f};

  int voff[4];
#pragma unroll
  for (int jc = 0; jc < 4; jc++)
    voff[jc] = (w * 64 + jc * 16 + l16) * 1024 + quad * 8;
  int pbase[4];
#pragma unroll
  for (int i = 0; i < 4; i++) pbase[i] = (i * 16 + l16) * 1024;

#define LDV(VF, KS)                                               \
  _Pragma("unroll") for (int t = 0; t < 4; t++)                   \
    VF[t] = *(const bf16x8*)(vb + voff[t] + (KS) * 32);
#define LDP(PF, KS)                                               \
  _Pragma("unroll") for (int t = 0; t < 4; t++)                   \
    PF[t] = *(const bf16x8*)&Ps[pbase[t] + ((((KS) * 4 + quad) ^ xr) << 3)];
#define MM2(PF, VF)                                               \
  __builtin_amdgcn_s_setprio(1);                                  \
  _Pragma("unroll") for (int i = 0; i < 4; i++)                   \
    _Pragma("unroll") for (int jc = 0; jc < 4; jc++)              \
      o[i][jc] = __builtin_amdgcn_mfma_f32_16x16x32_bf16(         \
          PF[i], VF[jc], o[i][jc], 0, 0, 0);                      \
  __builtin_amdgcn_s_setprio(0);

  {
    bf16x8 vA[4], vB[4];
    LDV(vA, 0)
#pragma unroll
    for (int ks2 = 0; ks2 < 16; ks2++) {
      bf16x8 pA[4], pB[4];
      LDP(pA, 2 * ks2)
      LDV(vB, 2 * ks2 + 1)
      MM2(pA, vA)
      LDP(pB, 2 * ks2 + 1)
      if (ks2 < 15) { LDV(vA, 2 * ks2 + 2) }
      MM2(pB, vB)
    }
  }
#undef LDV
#undef LDP
#undef MM2

  // ---------------- epilogue: scale by 1/l, transpose, store ----------------
  sync_lds();  // all waves done reading P before obuf overwrite
  f32x4 li[4];
#pragma unroll
  for (int i = 0; i < 4; i++) li[i] = *(f32x4*)&linv[i * 16 + quad * 4];

  UST* obuf = Ps;  // 64 rows x pitch 520 UST
#pragma unroll
  for (int i = 0; i < 4; i++)
#pragma unroll
    for (int jc = 0; jc < 4; jc++)
#pragma unroll
      for (int r = 0; r < 4; r++)
        obuf[(i * 16 + quad * 4 + r) * 520 + w * 64 + jc * 16 + l16] =
            f2bf(o[i][jc][r] * li[i][r]);
  sync_lds();
#pragma unroll
  for (int it = 0; it < 8; ++it) {
    int q = tid + it * 512;
    int row = q >> 6, cc = q & 63;  // 64 rows x 64 us8-chunks = full 512 cols
    us8 vv = *(us8*)&obuf[row * 520 + cc * 8];
    *(us8*)&ob[(size_t)row * 512 + cc * 8] = vv;
  }
}

// ---- gemm_bt v5 (proven): 128x128, 4 waves, gload_lds, depth-2 vmcnt(4) ----
template <int EPI, int NT, int AR, int BR>
__global__ __launch_bounds__(256, 4) void gemm_bt(
    const UST* __restrict__ A, const UST* __restrict__ B, void* __restrict__ C,
    const float* __restrict__ bias, const float* __restrict__ extra, float scale,
    int K, int ldc,
    int rsA, int csA, int ssA, int rsB, int csB, int ssB,
    long zA, long zB, long zC) {
  __shared__ __align__(16) UST buf[16384];

  const int tid = threadIdx.x;
  int m0, n0, z;
  if constexpr (NT > 0) {
    int lin = blockIdx.x + NT * (blockIdx.y + gridDim.y * blockIdx.z);
    int T = gridDim.y * gridDim.z;
    int per = T >> 3;
    int g = lin & 7, idx = lin >> 3;
    int at = g * per + idx / NT;
    int x = idx % NT;
    m0 = (at % gridDim.y) * 128; z = at / gridDim.y; n0 = x * 128;
  } else {
    m0 = blockIdx.y * 128; n0 = blockIdx.x * 128; z = blockIdx.z;
  }
  const UST* Ab = A + (long)z * zA;
  const UST* Bb = B + (long)z * zB;

  const int w = tid >> 6, lane = tid & 63;
  const int quad = lane >> 4, l16 = lane & 15;
  const int wm = w >> 1, wn = w & 1;

  f32x4 acc[4][4];
#pragma unroll
  for (int i = 0; i < 4; i++)
#pragma unroll
    for (int j = 0; j < 4; j++) acc[i][j] = f32x4{0.f, 0.f, 0.f, 0.f};

  const UST* gA[2];
  const UST* gB[2];
#pragma unroll
  for (int t = 0; t < 2; t++) {
    int q = t * 256 + w * 64 + lane;
    int row, kc;
    if constexpr (AR) { kc = q >> 7; row = q & 127; }
    else {
      row = q >> 2; int kk = q & 3;
      kc = kk ^ (((row >> 1) ^ (row >> 3)) & 3);
    }
    gA[t] = Ab + (size_t)(m0 + row) * rsA + (size_t)kc * csA;
  }
#pragma unroll
  for (int t = 0; t < 2; t++) {
    int q = t * 256 + w * 64 + lane;
    int row, kc;
    if constexpr (BR) { kc = q >> 7; row = q & 127; }
    else {
      row = q >> 2; int kk = q & 3;
      kc = kk ^ (((row >> 1) ^ (row >> 3)) & 3);
    }
    gB[t] = Bb + (size_t)(n0 + row) * rsB + (size_t)kc * csB;
  }
  int aoff[4], boff[4];
#pragma unroll
  for (int i = 0; i < 4; i++) {
    int R = wm * 64 + i * 16 + l16;
    if constexpr (AR) aoff[i] = quad * 1024 + R * 8;
    else {
      int s = ((R >> 1) ^ (R >> 3)) & 3;
      aoff[i] = R * 32 + (quad ^ s) * 8;
    }
  }
#pragma unroll
  for (int j = 0; j < 4; j++) {
    int R = wn * 64 + j * 16 + l16;
    if constexpr (BR) boff[j] = quad * 1024 + R * 8;
    else {
      int s = ((R >> 1) ^ (R >> 3)) & 3;
      boff[j] = R * 32 + (quad ^ s) * 8;
    }
  }

  const int nk = K >> 5;

#define STAGE(bb)                                   \
  {                                                 \
    UST* sA = buf + (bb) * 8192;                    \
    UST* sB = sA + 4096;                            \
    _Pragma("unroll") for (int t = 0; t < 2; t++) { \
      gload16(gA[t], sA + t * 2048 + w * 512);      \
      gA[t] += ssA;                                 \
    }                                               \
    _Pragma("unroll") for (int t = 0; t < 2; t++) { \
      gload16(gB[t], sB + t * 2048 + w * 512);      \
      gB[t] += ssB;                                 \
    }                                               \
  }

  STAGE(0)
  STAGE(1)

  for (int k = 0; k < nk; ++k) {
    if (k + 1 < nk) asm volatile("s_waitcnt vmcnt(4)" ::: "memory");
    else            asm volatile("s_waitcnt vmcnt(0)" ::: "memory");
    barrier_nowait();
    const UST* cA = buf + (k & 1) * 8192;
    const UST* cB = cA + 4096;
    bf16x8 af[4], bfr[4];
#pragma unroll
    for (int i = 0; i < 4; i++) af[i] = *(const bf16x8*)(cA + aoff[i]);
#pragma unroll
    for (int j = 0; j < 4; j++) bfr[j] = *(const bf16x8*)(cB + boff[j]);
    __builtin_amdgcn_s_setprio(1);
#pragma unroll
    for (int i = 0; i < 4; i++)
#pragma unroll
      for (int j = 0; j < 4; j++)
        acc[i][j] = __builtin_amdgcn_mfma_f32_16x16x32_bf16(af[i], bfr[j], acc[i][j], 0, 0, 0);
    __builtin_amdgcn_s_setprio(0);
    if (k + 2 < nk) {
      sync_lds();
      STAGE(k & 1)
    }
  }
  sync_lds();

  if constexpr (EPI == 4) {
    float* fbuf = (float*)buf;
    float* Cb = (float*)C + (long)z * zC;
    const float* Eb = extra + (long)z * zC;
#pragma unroll
    for (int p = 0; p < 4; ++p) {
      if (p) barrier_nowait();
      if (wm == (p >> 1)) {
#pragma unroll
        for (int ii = 0; ii < 2; ii++) {
          const int i = (p & 1) * 2 + ii;
#pragma unroll
          for (int j = 0; j < 4; j++)
#pragma unroll
            for (int r = 0; r < 4; r++)
              fbuf[(ii * 16 + quad * 4 + r) * 132 + wn * 64 + j * 16 + l16] = acc[i][j][r];
        }
      }
      sync_lds();
#pragma unroll
      for (int it = 0; it < 4; ++it) {
        int q = tid + it * 256;
        int row = q >> 5, colc = q & 31;
        int gr = m0 + p * 32 + row;
        size_t off = (size_t)gr * ldc + n0 + colc * 4;
        float4 v = *(float4*)&fbuf[row * 132 + colc * 4];
        float4 e = *(const float4*)&Eb[off];
        float bb = bias[gr];
        v.x += bb + e.x; v.y += bb + e.y; v.z += bb + e.z; v.w += bb + e.w;
        *(float4*)&Cb[off] = v;
      }
    }
  } else {  // EPI 6: QKV
    const bool vreg = (n0 >= 1024);
    if (!vreg) {
      UST* Cb = (UST*)C + (long)z * zC;
#pragma unroll
      for (int h = 0; h < 2; ++h) {
        if (h) barrier_nowait();
        if (wm == h) {
#pragma unroll
          for (int i = 0; i < 4; i++)
#pragma unroll
            for (int j = 0; j < 4; j++) {
              const float bc = bias[n0 + wn * 64 + j * 16 + l16];
#pragma unroll
              for (int r = 0; r < 4; r++)
                buf[(i * 16 + quad * 4 + r) * 136 + wn * 64 + j * 16 + l16] =
                    f2bf(acc[i][j][r] + bc);
            }
        }
        sync_lds();
#pragma unroll
        for (int it = 0; it < 4; ++it) {
          int q = tid + it * 256;
          int row = q >> 4, colc = q & 15;
          us8 v = *(us8*)&buf[row * 136 + colc * 8];
          *(us8*)&Cb[(size_t)(m0 + h * 64 + row) * ldc + n0 + colc * 8] = v;
        }
      }
    } else {
      UST* Vb = (UST*)extra + (long)z * 524288;
#pragma unroll
      for (int h = 0; h < 2; ++h) {
        if (h) barrier_nowait();
        if (wn == h) {
#pragma unroll
          for (int i = 0; i < 4; i++)
#pragma unroll
            for (int j = 0; j < 4; j++) {
              const float bc = bias[n0 + wn * 64 + j * 16 + l16];
              ushort4 sv;
              sv.x = f2bf(acc[i][j][0] + bc);
              sv.y = f2bf(acc[i][j][1] + bc);
              sv.z = f2bf(acc[i][j][2] + bc);
              sv.w = f2bf(acc[i][j][3] + bc);
              *(ushort4*)&buf[(j * 16 + l16) * 136 + wm * 64 + i * 16 + quad * 4] = sv;
            }
        }
        sync_lds();
#pragma unroll
        for (int it = 0; it < 4; ++it) {
          int q = tid + it * 256;
          int c = q >> 4, mc = q & 15;
          us8 v = *(us8*)&buf[c * 136 + mc * 8];
          *(us8*)&Vb[(size_t)(n0 - 1024 + h * 64 + c) * 1024 + m0 + mc * 8] = v;
        }
      }
    }
  }
#undef STAGE
}

extern "C" void kernel_launch(void* const* d_in, const int* in_sizes, int n_in,
                              void* d_out, int out_size, void* d_ws, size_t ws_size,
                              hipStream_t stream) {
  const float* inp   = (const float*)d_in[0];
  const float* gamma = (const float*)d_in[1];
  const float* beta  = (const float*)d_in[2];
  const float* Wq    = (const float*)d_in[3];
  const float* bq    = (const float*)d_in[4];
  const float* Wk    = (const float*)d_in[5];
  const float* bk    = (const float*)d_in[6];
  const float* Wv    = (const float*)d_in[7];
  const float* bv    = (const float*)d_in[8];
  const float* Wo    = (const float*)d_in[9];
  const float* bo    = (const float*)d_in[10];
  float* out = (float*)d_out;
  char* ws = (char*)d_ws;

  UST*   Xnt   = (UST*)(ws);                           // 16 MB; reused as At
  UST*   QKt   = (UST*)(ws + ((size_t)16 << 20));      // 32 MB (b,n,1024)
  UST*   V     = (UST*)(ws + ((size_t)48 << 20));      // 16 MB (b,c,m)
  float* bqkv  = (float*)(ws + ((size_t)96 << 20));    // 6 KB
  UST*   Wqkvb = (UST*)(ws + ((size_t)96 << 20) + 8192);  // 1.5 MB
  UST*   Wob   = Wqkvb + 786432;                       // 512 KB
  UST*   At    = Xnt;

  prep<<<768, 256, 0, stream>>>(
      inp, gamma, beta, Xnt,
      (const float4*)Wq, (const float4*)Wk, (const float4*)Wv, (const float4*)Wo,
      (ushort4*)Wqkvb, (ushort4*)Wob,
      (const float4*)bq, (const float4*)bk, (const float4*)bv, (float4*)bqkv);

  // QKV (v5, proven): cols 0..1023 -> QKt ; cols 1024..1535 -> V^T
  gemm_bt<6, 12, 1, 0><<<dim3(12, 8, 16), 256, 0, stream>>>(
      Xnt, Wqkvb, QKt, bqkv, (const float*)V, 1.f,
      512, 1024, 8, 8192, 32768, 512, 8, 32, 524288, 0, 1048576);
  // fused attention: At = softmax(Q K^T / sqrt(512)) @ V^T   (P stays in LDS)
  attn<<<256, 512, 0, stream>>>(QKt, V, At, 0.04419417382415922f);
  // out = Wo At^T + bo[row] + inp
  gemm_bt<4, 8, 0, 0><<<dim3(8, 4, 16), 256, 0, stream>>>(
      Wob, At, out, bo, inp, 1.f,
      512, 1024, 512, 8, 32, 512, 8, 32, 0, 524288, 524288);
}

// Round 9
// 216.174 us; speedup vs baseline: 1.1614x; 1.1614x over previous
//
#include <hip/hip_runtime.h>

typedef unsigned short UST;
typedef __attribute__((ext_vector_type(8))) short bf16x8;
typedef __attribute__((ext_vector_type(8))) unsigned short us8;
typedef __attribute__((ext_vector_type(4))) float f32x4;

__device__ __forceinline__ UST f2bf(float f) {
  union { float f; unsigned int u; } x; x.f = f;
  unsigned int r = x.u + 0x7fffu + ((x.u >> 16) & 1u);
  return (UST)(r >> 16);
}
__device__ __forceinline__ float bf2f(UST h) {
  union { unsigned int u; float f; } x; x.u = ((unsigned int)h) << 16;
  return x.f;
}

// sync_lds drains LDS ops only (NOT vmcnt) then barriers.
__device__ __forceinline__ void sync_lds() {
  asm volatile("s_waitcnt lgkmcnt(0)\n\ts_barrier" ::: "memory");
}
__device__ __forceinline__ void barrier_nowait() {
  asm volatile("s_barrier" ::: "memory");
}

typedef const __attribute__((address_space(1))) void g_void;
typedef __attribute__((address_space(3))) void lds_void;
__device__ __forceinline__ void gload16(const UST* g, UST* l) {
  __builtin_amdgcn_global_load_lds((g_void*)g, (lds_void*)l, 16, 0, 0);
}

// ---- prep: GroupNorm (single pass) + weight conversion + zero l ------------
__global__ __launch_bounds__(256) void prep(
    const float* __restrict__ inp, const float* __restrict__ gamma,
    const float* __restrict__ beta, UST* __restrict__ Xnt,
    const float4* __restrict__ wq, const float4* __restrict__ wk,
    const float4* __restrict__ wv, const float4* __restrict__ wo,
    ushort4* __restrict__ oqkv, ushort4* __restrict__ owo,
    const float4* __restrict__ bq4, const float4* __restrict__ bk4,
    const float4* __restrict__ bv4, float4* __restrict__ bqkv4,
    float4* __restrict__ l4) {
  const int tid = threadIdx.x;
  if (blockIdx.x >= 768) {  // zero the softmax-denominator array (16384 f32)
    int i = (blockIdx.x - 768) * 256 + tid;
    l4[i] = make_float4(0.f, 0.f, 0.f, 0.f);
    return;
  }
  if (blockIdx.x >= 512) {
    const int wb = blockIdx.x - 512;
    int i = wb * 256 + tid;
    float4 v;
    v = wq[i]; oqkv[i]          = make_ushort4(f2bf(v.x), f2bf(v.y), f2bf(v.z), f2bf(v.w));
    v = wk[i]; oqkv[i + 65536]  = make_ushort4(f2bf(v.x), f2bf(v.y), f2bf(v.z), f2bf(v.w));
    v = wv[i]; oqkv[i + 131072] = make_ushort4(f2bf(v.x), f2bf(v.y), f2bf(v.z), f2bf(v.w));
    v = wo[i]; owo[i]           = make_ushort4(f2bf(v.x), f2bf(v.y), f2bf(v.z), f2bf(v.w));
    if (wb < 2) {
      int t = wb * 256 + tid;
      if (t < 384) bqkv4[t] = (t < 128) ? bq4[t] : (t < 256 ? bk4[t - 128] : bv4[t - 256]);
    }
    return;
  }
  // GroupNorm: one block per (batch b, group g); data held in 64 VGPRs.
  const int g = blockIdx.x & 31, b = blockIdx.x >> 5;
  const float4* p4 = (const float4*)(inp + ((size_t)b * 32 + g) * 16384);
  float x[16][4];
  float s = 0.f, ss = 0.f;
#pragma unroll
  for (int i = 0; i < 16; i++) {
    float4 t = p4[tid + i * 256];
    x[i][0] = t.x; x[i][1] = t.y; x[i][2] = t.z; x[i][3] = t.w;
    s += t.x + t.y + t.z + t.w;
    ss += t.x * t.x + t.y * t.y + t.z * t.z + t.w * t.w;
  }
  for (int o = 32; o >= 1; o >>= 1) { s += __shfl_xor(s, o); ss += __shfl_xor(ss, o); }
  __shared__ float red[8];
  __shared__ float mu_s, rstd_s;
  const int w = tid >> 6;
  if ((tid & 63) == 0) { red[w * 2] = s; red[w * 2 + 1] = ss; }
  __syncthreads();
  if (tid == 0) {
    float S1 = red[0] + red[2] + red[4] + red[6];
    float S2 = red[1] + red[3] + red[5] + red[7];
    float mu = S1 * (1.f / 16384.f);
    float var = S2 * (1.f / 16384.f) - mu * mu;
    mu_s = mu; rstd_s = rsqrtf(var + 1e-6f);
  }
  __syncthreads();
  const float mu = mu_s, rstd = rstd_s;
#pragma unroll
  for (int o2 = 0; o2 < 2; o2++) {
    const int ccg = g * 2 + o2;
    float sc[8], sh[8];
#pragma unroll
    for (int j = 0; j < 8; j++) {
      int ch = ccg * 8 + j;
      sc[j] = gamma[ch] * rstd;
      sh[j] = beta[ch] - mu * sc[j];
    }
#pragma unroll
    for (int m = 0; m < 4; m++) {
      us8 v;
#pragma unroll
      for (int j = 0; j < 8; j++) v[j] = f2bf(x[o2 * 8 + j][m] * sc[j] + sh[j]);
      *(us8*)(Xnt + (size_t)b * 524288 + (size_t)ccg * 8192 + (size_t)(4 * tid + m) * 8) = v;
    }
  }
}

// ---- gemm_bt v5.1: 128x128, 4 waves, gload_lds, depth-2 vmcnt(4) -----------
// = r4's proven v5 with s_setprio REMOVED from the K-loop (m190: setprio is
// null-to-negative on barrier-lockstep pre-8-phase GEMMs; it belongs only to
// phase-split schedules). Everything else bit-identical to the 213.4us state.
template <int EPI, int NT, int AR, int BR>
__global__ __launch_bounds__(256, 4) void gemm_bt(
    const UST* __restrict__ A, const UST* __restrict__ B, void* __restrict__ C,
    const float* __restrict__ bias, const float* __restrict__ extra, float scale,
    int K, int ldc,
    int rsA, int csA, int ssA, int rsB, int csB, int ssB,
    long zA, long zB, long zC) {
  __shared__ __align__(16) UST buf[16384];

  const int tid = threadIdx.x;
  int m0, n0, z;
  if constexpr (NT > 0) {
    int lin = blockIdx.x + NT * (blockIdx.y + gridDim.y * blockIdx.z);
    int T = gridDim.y * gridDim.z;
    int per = T >> 3;
    int g = lin & 7, idx = lin >> 3;
    int at = g * per + idx / NT;
    int x = idx % NT;
    m0 = (at % gridDim.y) * 128; z = at / gridDim.y; n0 = x * 128;
  } else {
    m0 = blockIdx.y * 128; n0 = blockIdx.x * 128; z = blockIdx.z;
  }
  const UST* Ab = A + (long)z * zA;
  const UST* Bb = B + (long)z * zB;

  const int w = tid >> 6, lane = tid & 63;
  const int quad = lane >> 4, l16 = lane & 15;
  const int wm = w >> 1, wn = w & 1;

  f32x4 acc[4][4];
#pragma unroll
  for (int i = 0; i < 4; i++)
#pragma unroll
    for (int j = 0; j < 4; j++) acc[i][j] = f32x4{0.f, 0.f, 0.f, 0.f};

  const UST* gA[2];
  const UST* gB[2];
#pragma unroll
  for (int t = 0; t < 2; t++) {
    int q = t * 256 + w * 64 + lane;
    int row, kc;
    if constexpr (AR) { kc = q >> 7; row = q & 127; }
    else {
      row = q >> 2; int kk = q & 3;
      kc = kk ^ (((row >> 1) ^ (row >> 3)) & 3);
    }
    gA[t] = Ab + (size_t)(m0 + row) * rsA + (size_t)kc * csA;
  }
#pragma unroll
  for (int t = 0; t < 2; t++) {
    int q = t * 256 + w * 64 + lane;
    int row, kc;
    if constexpr (BR) { kc = q >> 7; row = q & 127; }
    else {
      row = q >> 2; int kk = q & 3;
      kc = kk ^ (((row >> 1) ^ (row >> 3)) & 3);
    }
    gB[t] = Bb + (size_t)(n0 + row) * rsB + (size_t)kc * csB;
  }
  int aoff[4], boff[4];
#pragma unroll
  for (int i = 0; i < 4; i++) {
    int R = wm * 64 + i * 16 + l16;
    if constexpr (AR) aoff[i] = quad * 1024 + R * 8;
    else {
      int s = ((R >> 1) ^ (R >> 3)) & 3;
      aoff[i] = R * 32 + (quad ^ s) * 8;
    }
  }
#pragma unroll
  for (int j = 0; j < 4; j++) {
    int R = wn * 64 + j * 16 + l16;
    if constexpr (BR) boff[j] = quad * 1024 + R * 8;
    else {
      int s = ((R >> 1) ^ (R >> 3)) & 3;
      boff[j] = R * 32 + (quad ^ s) * 8;
    }
  }

  const int nk = K >> 5;

#define STAGE(bb)                                   \
  {                                                 \
    UST* sA = buf + (bb) * 8192;                    \
    UST* sB = sA + 4096;                            \
    _Pragma("unroll") for (int t = 0; t < 2; t++) { \
      gload16(gA[t], sA + t * 2048 + w * 512);      \
      gA[t] += ssA;                                 \
    }                                               \
    _Pragma("unroll") for (int t = 0; t < 2; t++) { \
      gload16(gB[t], sB + t * 2048 + w * 512);      \
      gB[t] += ssB;                                 \
    }                                               \
  }

  STAGE(0)
  STAGE(1)

  for (int k = 0; k < nk; ++k) {
    if (k + 1 < nk) asm volatile("s_waitcnt vmcnt(4)" ::: "memory");
    else            asm volatile("s_waitcnt vmcnt(0)" ::: "memory");
    barrier_nowait();
    const UST* cA = buf + (k & 1) * 8192;
    const UST* cB = cA + 4096;
    bf16x8 af[4], bfr[4];
#pragma unroll
    for (int i = 0; i < 4; i++) af[i] = *(const bf16x8*)(cA + aoff[i]);
#pragma unroll
    for (int j = 0; j < 4; j++) bfr[j] = *(const bf16x8*)(cB + boff[j]);
#pragma unroll
    for (int i = 0; i < 4; i++)
#pragma unroll
      for (int j = 0; j < 4; j++)
        acc[i][j] = __builtin_amdgcn_mfma_f32_16x16x32_bf16(af[i], bfr[j], acc[i][j], 0, 0, 0);
    if (k + 2 < nk) {
      sync_lds();
      STAGE(k & 1)
    }
  }
  sync_lds();

  if constexpr (EPI == 4) {
    float* fbuf = (float*)buf;
    float* Cb = (float*)C + (long)z * zC;
    const float* Eb = extra + (long)z * zC;
#pragma unroll
    for (int p = 0; p < 4; ++p) {
      if (p) barrier_nowait();
      if (wm == (p >> 1)) {
#pragma unroll
        for (int ii = 0; ii < 2; ii++) {
          const int i = (p & 1) * 2 + ii;
#pragma unroll
          for (int j = 0; j < 4; j++)
#pragma unroll
            for (int r = 0; r < 4; r++)
              fbuf[(ii * 16 + quad * 4 + r) * 132 + wn * 64 + j * 16 + l16] = acc[i][j][r];
        }
      }
      sync_lds();
#pragma unroll
      for (int it = 0; it < 4; ++it) {
        int q = tid + it * 256;
        int row = q >> 5, colc = q & 31;
        int gr = m0 + p * 32 + row;
        size_t off = (size_t)gr * ldc + n0 + colc * 4;
        float4 v = *(float4*)&fbuf[row * 132 + colc * 4];
        float4 e = *(const float4*)&Eb[off];
        float bb = bias[gr];
        v.x += bb + e.x; v.y += bb + e.y; v.z += bb + e.z; v.w += bb + e.w;
        *(float4*)&Cb[off] = v;
      }
    }
  } else if constexpr (EPI == 7) {
    UST* Cb = (UST*)C + (long)z * zC;
    float* lrow = (float*)extra + (long)z * 1024;
#pragma unroll
    for (int h = 0; h < 2; ++h) {
      if (h) barrier_nowait();
      if (wm == h) {
#pragma unroll
        for (int i = 0; i < 4; i++)
#pragma unroll
          for (int j = 0; j < 4; j++)
#pragma unroll
            for (int r = 0; r < 4; r++) {
              float v = __expf(acc[i][j][r] * scale);
              buf[(i * 16 + quad * 4 + r) * 136 + wn * 64 + j * 16 + l16] = f2bf(v);
            }
      }
      sync_lds();
#pragma unroll
      for (int it = 0; it < 4; ++it) {
        int q = tid + it * 256;
        int row = q >> 4, colc = q & 15;
        us8 v = *(us8*)&buf[row * 136 + colc * 8];
        *(us8*)&Cb[(size_t)(m0 + h * 64 + row) * ldc + n0 + colc * 8] = v;
        float s = 0.f;
#pragma unroll
        for (int j = 0; j < 8; j++) s += bf2f(v[j]);
        s += __shfl_xor(s, 8); s += __shfl_xor(s, 4);
        s += __shfl_xor(s, 2); s += __shfl_xor(s, 1);
        if ((lane & 15) == 0) atomicAdd(&lrow[m0 + h * 64 + row], s);
      }
    }
  } else if constexpr (EPI == 8) {
    UST* Cb = (UST*)C + (long)z * zC;
    const float* lrow = bias + (long)z * 1024;
#pragma unroll
    for (int h = 0; h < 2; ++h) {
      if (h) barrier_nowait();
      if (wm == h) {
#pragma unroll
        for (int i = 0; i < 4; i++) {
          float rs[4];
#pragma unroll
          for (int r = 0; r < 4; r++)
            rs[r] = 1.0f / lrow[m0 + h * 64 + i * 16 + quad * 4 + r];
#pragma unroll
          for (int j = 0; j < 4; j++)
#pragma unroll
            for (int r = 0; r < 4; r++)
              buf[(i * 16 + quad * 4 + r) * 136 + wn * 64 + j * 16 + l16] =
                  f2bf(acc[i][j][r] * rs[r]);
        }
      }
      sync_lds();
#pragma unroll
      for (int it = 0; it < 4; ++it) {
        int q = tid + it * 256;
        int row = q >> 4, colc = q & 15;
        us8 v = *(us8*)&buf[row * 136 + colc * 8];
        *(us8*)&Cb[(size_t)(m0 + h * 64 + row) * ldc + n0 + colc * 8] = v;
      }
    }
  } else {  // EPI 6: QKV
    const bool vreg = (n0 >= 1024);
    if (!vreg) {
      UST* Cb = (UST*)C + (long)z * zC;
#pragma unroll
      for (int h = 0; h < 2; ++h) {
        if (h) barrier_nowait();
        if (wm == h) {
#pragma unroll
          for (int i = 0; i < 4; i++)
#pragma unroll
            for (int j = 0; j < 4; j++) {
              const float bc = bias[n0 + wn * 64 + j * 16 + l16];
#pragma unroll
              for (int r = 0; r < 4; r++)
                buf[(i * 16 + quad * 4 + r) * 136 + wn * 64 + j * 16 + l16] =
                    f2bf(acc[i][j][r] + bc);
            }
        }
        sync_lds();
#pragma unroll
        for (int it = 0; it < 4; ++it) {
          int q = tid + it * 256;
          int row = q >> 4, colc = q & 15;
          us8 v = *(us8*)&buf[row * 136 + colc * 8];
          *(us8*)&Cb[(size_t)(m0 + h * 64 + row) * ldc + n0 + colc * 8] = v;
        }
      }
    } else {
      UST* Vb = (UST*)extra + (long)z * 524288;
#pragma unroll
      for (int h = 0; h < 2; ++h) {
        if (h) barrier_nowait();
        if (wn == h) {
#pragma unroll
          for (int i = 0; i < 4; i++)
#pragma unroll
            for (int j = 0; j < 4; j++) {
              const float bc = bias[n0 + wn * 64 + j * 16 + l16];
              ushort4 sv;
              sv.x = f2bf(acc[i][j][0] + bc);
              sv.y = f2bf(acc[i][j][1] + bc);
              sv.z = f2bf(acc[i][j][2] + bc);
              sv.w = f2bf(acc[i][j][3] + bc);
              *(ushort4*)&buf[(j * 16 + l16) * 136 + wm * 64 + i * 16 + quad * 4] = sv;
            }
        }
        sync_lds();
#pragma unroll
        for (int it = 0; it < 4; ++it) {
          int q = tid + it * 256;
          int c = q >> 4, mc = q & 15;
          us8 v = *(us8*)&buf[c * 136 + mc * 8];
          *(us8*)&Vb[(size_t)(n0 - 1024 + h * 64 + c) * 1024 + m0 + mc * 8] = v;
        }
      }
    }
  }
#undef STAGE
}

extern "C" void kernel_launch(void* const* d_in, const int* in_sizes, int n_in,
                              void* d_out, int out_size, void* d_ws, size_t ws_size,
                              hipStream_t stream) {
  const float* inp   = (const float*)d_in[0];
  const float* gamma = (const float*)d_in[1];
  const float* beta  = (const float*)d_in[2];
  const float* Wq    = (const float*)d_in[3];
  const float* bq    = (const float*)d_in[4];
  const float* Wk    = (const float*)d_in[5];
  const float* bk    = (const float*)d_in[6];
  const float* Wv    = (const float*)d_in[7];
  const float* bv    = (const float*)d_in[8];
  const float* Wo    = (const float*)d_in[9];
  const float* bo    = (const float*)d_in[10];
  float* out = (float*)d_out;
  char* ws = (char*)d_ws;

  UST*   Xnt   = (UST*)(ws);                           // 16 MB; reused as At
  UST*   QKt   = (UST*)(ws + ((size_t)16 << 20));      // 32 MB (b,n,1024)
  UST*   V     = (UST*)(ws + ((size_t)48 << 20));      // 16 MB (b,c,m)
  UST*   P     = (UST*)(ws + ((size_t)64 << 20));      // 32 MB (b,n,m)
  float* bqkv  = (float*)(ws + ((size_t)96 << 20));    // 6 KB
  UST*   Wqkvb = (UST*)(ws + ((size_t)96 << 20) + 8192);  // 1.5 MB
  UST*   Wob   = Wqkvb + 786432;                       // 512 KB
  float* l     = (float*)(ws + ((size_t)100 << 20));   // 64 KB
  UST*   At    = Xnt;

  prep<<<784, 256, 0, stream>>>(
      inp, gamma, beta, Xnt,
      (const float4*)Wq, (const float4*)Wk, (const float4*)Wv, (const float4*)Wo,
      (ushort4*)Wqkvb, (ushort4*)Wob,
      (const float4*)bq, (const float4*)bk, (const float4*)bv, (float4*)bqkv,
      (float4*)l);

  // QKV: cols 0..1023 -> QKt ; cols 1024..1535 -> V (transposed)
  gemm_bt<6, 12, 1, 0><<<dim3(12, 8, 16), 256, 0, stream>>>(
      Xnt, Wqkvb, QKt, bqkv, (const float*)V, 1.f,
      512, 1024, 8, 8192, 32768, 512, 8, 32, 524288, 0, 1048576);
  // P = exp(Q K^T * scale), row sums -> l (atomic)
  gemm_bt<7, 8, 0, 0><<<dim3(8, 8, 16), 256, 0, stream>>>(
      QKt, QKt + 512, P, nullptr, (const float*)l, 0.04419417382415922f,
      512, 1024, 1024, 8, 32, 1024, 8, 32, 1048576, 1048576, 1048576);
  // At = (P V^T) / l[row]
  gemm_bt<8, 4, 0, 0><<<dim3(4, 8, 16), 256, 0, stream>>>(
      P, V, At, (const float*)l, nullptr, 1.f,
      1024, 512, 1024, 8, 32, 1024, 8, 32, 1048576, 524288, 524288);
  // out = Wo At^T + bo[row] + inp
  gemm_bt<4, 8, 0, 0><<<dim3(8, 4, 16), 256, 0, stream>>>(
      Wob, At, out, bo, inp, 1.f,
      512, 1024, 512, 8, 32, 512, 8, 32, 0, 524288, 524288);
}